// Round 24
// baseline (135.725 us; speedup 1.0000x reference)
//
#include <hip/hip_runtime.h>
#include <stdint.h>

namespace {

typedef float v2f __attribute__((ext_vector_type(2)));
typedef int   v2i __attribute__((ext_vector_type(2)));

constexpr int H      = 32;    // LSTM_SIZE
constexpr int NEDGE  = 128;
constexpr float TINY   = 1.1754943508222875e-38f;  // finfo(f32).tiny
constexpr float L2E    = 1.4426950408889634f;      // log2(e)
constexpr float LN2    = 0.6931471805599453f;

__device__ __forceinline__ void tf_round(uint32_t& x0, uint32_t& x1, int r) {
  x0 += x1;
  x1 = (x1 << r) | (x1 >> (32 - r));
  x1 ^= x0;
}

// Threefry-2x32, 20 rounds — bit-exact JAX threefry2x32_p
__device__ __forceinline__ void tf2x32(uint32_t k0, uint32_t k1,
                                       uint32_t& x0, uint32_t& x1) {
  const uint32_t ks2 = k0 ^ k1 ^ 0x1BD11BDAu;
  x0 += k0; x1 += k1;
  tf_round(x0,x1,13); tf_round(x0,x1,15); tf_round(x0,x1,26); tf_round(x0,x1, 6);
  x0 += k1;  x1 += ks2 + 1u;
  tf_round(x0,x1,17); tf_round(x0,x1,29); tf_round(x0,x1,16); tf_round(x0,x1,24);
  x0 += ks2; x1 += k0 + 2u;
  tf_round(x0,x1,13); tf_round(x0,x1,15); tf_round(x0,x1,26); tf_round(x0,x1, 6);
  x0 += k0;  x1 += k1 + 3u;
  tf_round(x0,x1,17); tf_round(x0,x1,29); tf_round(x0,x1,16); tf_round(x0,x1,24);
  x0 += k1;  x1 += ks2 + 4u;
  tf_round(x0,x1,13); tf_round(x0,x1,15); tf_round(x0,x1,26); tf_round(x0,x1, 6);
  x0 += ks2; x1 += k0 + 5u;
}

// ---- native-instruction transcendentals
__device__ __forceinline__ float fexp(float x) {       // e^x
  return __builtin_amdgcn_exp2f(x * L2E);
}
__device__ __forceinline__ float flog(float x) {       // ln(x)
  return __builtin_amdgcn_logf(x) * LN2;
}
__device__ __forceinline__ float fsigmoid(float x) {   // 1/(1+e^-x)
  return __builtin_amdgcn_rcpf(1.0f + __builtin_amdgcn_exp2f(-x * L2E));
}
__device__ __forceinline__ float ftanh(float x) {
  const float ax = __builtin_fabsf(x);
  const float t  = __builtin_amdgcn_exp2f(ax * (-2.0f * L2E));  // e^(-2|x|)
  const float r  = (1.0f - t) * __builtin_amdgcn_rcpf(1.0f + t);
  return __builtin_copysignf(r, x);
}

__device__ __forceinline__ float rdlane(float v, int i) {
  return __int_as_float(__builtin_amdgcn_readlane(__float_as_int(v), i));
}

template <int CTRL>
__device__ __forceinline__ float dppf(float v) {
  return __int_as_float(__builtin_amdgcn_update_dpp(
      __float_as_int(v), __float_as_int(v), CTRL, 0xF, 0xF, false));
}

// 64-lane reductions: DPP butterfly within rows of 16, then 4 readlanes.
__device__ __forceinline__ float wave_sum64(float v) {
  v += dppf<0xB1>(v);
  v += dppf<0x4E>(v);
  v += dppf<0x141>(v);
  v += dppf<0x140>(v);
  return (rdlane(v, 15) + rdlane(v, 31)) + (rdlane(v, 47) + rdlane(v, 63));
}

__device__ __forceinline__ float wave_max64(float v) {
  v = fmaxf(v, dppf<0xB1>(v));
  v = fmaxf(v, dppf<0x4E>(v));
  v = fmaxf(v, dppf<0x141>(v));
  v = fmaxf(v, dppf<0x140>(v));
  return fmaxf(fmaxf(rdlane(v, 15), rdlane(v, 31)),
               fmaxf(rdlane(v, 47), rdlane(v, 63)));
}

__device__ __forceinline__ v2f pkfma(v2f a, v2f b, v2f c) {
  return __builtin_elementwise_fma(a, b, c);   // -> v_pk_fma_f32
}

// Cross-half swap (gfx950 VALU): r.x = g[lane&31] (i or g gate row),
// r.y = g[(lane&31)+32] (f or o gate row), identical in both halves.
__device__ __forceinline__ v2f permswap_pair(float g) {
  const v2i r = __builtin_amdgcn_permlane32_swap(
      __float_as_int(g), __float_as_int(g), false, false);
  return v2f{__int_as_float(r.x), __int_as_float(r.y)};
}

__global__ __launch_bounds__(192, 1)
void ctrl_kernel(const float* __restrict__ input_vars,
                 const float* __restrict__ W_ih0, const float* __restrict__ W_hh0,
                 const float* __restrict__ b_ih0, const float* __restrict__ b_hh0,
                 const float* __restrict__ W_ih1, const float* __restrict__ W_hh1,
                 const float* __restrict__ b_ih1, const float* __restrict__ b_hh1,
                 const float* __restrict__ embd,
                 const float* __restrict__ W_pred, const float* __restrict__ b_pred,
                 float* __restrict__ out) {
  const int tid  = threadIdx.x;  // w0: LSTM0; w1: LSTM1+sample (1 step behind); w2: PRNG
  const int lane = tid & 63;
  const int wid  = tid >> 6;
  const int rB   = lane + 64;

  __shared__ __align__(16) float embd_lds[65 * H];  // rows 0-63 embd, 64 = input
  __shared__ __align__(16) float xdot[65][128];     // W_ih0 rows . x_op (33.3 KiB)
  __shared__ __align__(16) float h0buf[2][H];       // w0 -> w1, by step parity
  __shared__ __align__(16) float gumbuf[4][64];     // w2 -> w1, 4-deep
  __shared__ __align__(16) float xfer[2][2][64];    // w1 -> w0: xdot rows, by step parity
  __shared__ __align__(16) float arch_lds[NEDGE];
  __shared__ int w1flag;                            // #samples published by w1

  if (tid == 0) w1flag = 0;

  // ---- staging: waves 0/1 stage embd + input row
  if (wid < 2) {
#pragma unroll
    for (int j = 0; j < 4; ++j)
      reinterpret_cast<float4*>(embd_lds)[(tid & 127) + 128 * j] =
          reinterpret_cast<const float4*>(embd)[(tid & 127) + 128 * j];
    if (tid < 8)
      reinterpret_cast<float4*>(&embd_lds[64 * H])[tid] =
          reinterpret_cast<const float4*>(input_vars)[tid];
  }

  // Register weights: wave0 = W_ih0 (table build) + W_hh0 (loop);
  //                   wave1 = W_ih1 + W_hh1 + W_pred.
  const float* WX = (wid == 1) ? W_ih1 : W_ih0;
  const float* WH = (wid == 1) ? W_hh1 : W_hh0;
  float4 wxA[8], wxB[8], whA[8], whB[8];
#pragma unroll
  for (int q = 0; q < 8; ++q) {
    wxA[q] = reinterpret_cast<const float4*>(WX + lane * H)[q];
    wxB[q] = reinterpret_cast<const float4*>(WX + rB * H)[q];
    whA[q] = reinterpret_cast<const float4*>(WH + lane * H)[q];
    whB[q] = reinterpret_cast<const float4*>(WH + rB * H)[q];
  }
  float4 wp4[8];
  if (wid == 1) {
#pragma unroll
    for (int q = 0; q < 8; ++q)
      wp4[q] = reinterpret_cast<const float4*>(W_pred + lane * H)[q];
  }
  const float bsum0A = b_ih0[lane] + b_hh0[lane];
  const float bsum0B = b_ih0[rB]   + b_hh0[rB];
  const float bsum1A = b_ih1[lane] + b_hh1[lane];
  const float bsum1B = b_ih1[rB]   + b_hh1[rB];
  const float bp = b_pred[lane];

  uint32_t k0 = 0u, k1 = 42u;          // key chain (wave2)
  uint32_t s0c = 0u, s1c = 0u;         // stashed subkey (cipher1 -> cipher2)

  // ---- wave2 prologue A: gum(0) + cipher1(1) stash (exact R23 sequence)
  if (wid == 2) {
    {
      uint32_t r0 = 0u, r1 = (uint32_t)(lane & 1);
      tf2x32(k0, k1, r0, r1);
      const uint32_t n0 = (uint32_t)__builtin_amdgcn_readlane((int)r0, 0);
      const uint32_t n1 = (uint32_t)__builtin_amdgcn_readlane((int)r1, 0);
      const uint32_t s0 = (uint32_t)__builtin_amdgcn_readlane((int)r0, 1);
      const uint32_t s1 = (uint32_t)__builtin_amdgcn_readlane((int)r1, 1);
      uint32_t x0 = 0u, x1 = (uint32_t)lane;
      tf2x32(s0, s1, x0, x1);
      const uint32_t bits = x0 ^ x1;
      k0 = n0; k1 = n1;
      float u = __uint_as_float(0x3f800000u | (bits >> 9)) - 1.0f;
      u = fmaxf(u + TINY, TINY);
      gumbuf[0][lane] = -flog(-flog(u));
    }
    {  // cipher1(1)
      uint32_t r0 = 0u, r1 = (uint32_t)(lane & 1);
      tf2x32(k0, k1, r0, r1);
      k0  = (uint32_t)__builtin_amdgcn_readlane((int)r0, 0);
      k1  = (uint32_t)__builtin_amdgcn_readlane((int)r1, 0);
      s0c = (uint32_t)__builtin_amdgcn_readlane((int)r0, 1);
      s1c = (uint32_t)__builtin_amdgcn_readlane((int)r1, 1);
    }
  }
  __syncthreads();   // embd staged, gum(0) ready

#define W2_STEP(GIDX)                                                       \
  {                                                                         \
    uint32_t x0 = 0u, x1 = (uint32_t)lane;                                  \
    tf2x32(s0c, s1c, x0, x1);                                               \
    const uint32_t bits = x0 ^ x1;                                          \
    float u = __uint_as_float(0x3f800000u | (bits >> 9)) - 1.0f;            \
    u = fmaxf(u + TINY, TINY);                                              \
    gumbuf[(GIDX) & 3][lane] = -flog(-flog(u));                             \
    uint32_t r0 = 0u, r1 = (uint32_t)(lane & 1);                            \
    tf2x32(k0, k1, r0, r1);                                                 \
    k0  = (uint32_t)__builtin_amdgcn_readlane((int)r0, 0);                  \
    k1  = (uint32_t)__builtin_amdgcn_readlane((int)r1, 0);                  \
    s0c = (uint32_t)__builtin_amdgcn_readlane((int)r0, 1);                  \
    s1c = (uint32_t)__builtin_amdgcn_readlane((int)r1, 1);                  \
  }

  // ---- phase 0: wave0 builds xdot table; wave2: gum(1) + cipher1(2)
  if (wid == 0) {
    for (int op = 0; op < 65; ++op) {
      v2f xA01={0.f,0.f}, xA23={0.f,0.f}, xB01={0.f,0.f}, xB23={0.f,0.f};
#pragma unroll
      for (int q = 0; q < 8; ++q) {
        const float4 x4 =
            *reinterpret_cast<const float4*>(&embd_lds[op * H + 4 * q]);
        xA01 = pkfma(v2f{x4.x, x4.y}, v2f{wxA[q].x, wxA[q].y}, xA01);
        xA23 = pkfma(v2f{x4.z, x4.w}, v2f{wxA[q].z, wxA[q].w}, xA23);
        xB01 = pkfma(v2f{x4.x, x4.y}, v2f{wxB[q].x, wxB[q].y}, xB01);
        xB23 = pkfma(v2f{x4.z, x4.w}, v2f{wxB[q].z, wxB[q].w}, xB23);
      }
      xdot[op][lane] = (xA01.x + xA01.y) + (xA23.x + xA23.y);
      xdot[op][rB]   = (xB01.x + xB01.y) + (xB23.x + xB23.y);
    }
  } else if (wid == 2) {
    W2_STEP(1)
  }
  __syncthreads();   // table + gum(1)

  // ---- phase 1: wave0 computes h0(0); wave2: gum(2) + cipher1(3)
  float c0 = 0.f, h0v = 0.f;
  v2f hoA01={0.f,0.f}, hoA23={0.f,0.f}, hoB01={0.f,0.f}, hoB23={0.f,0.f};
  if (wid == 0) {
    const float xdA = xdot[64][lane];
    const float xdB = xdot[64][rB];
    const float gA = (bsum0A + xdA)
                   + ((hoA01.x + hoA01.y) + (hoA23.x + hoA23.y));
    const float gB = (bsum0B + xdB)
                   + ((hoB01.x + hoB01.y) + (hoB23.x + hoB23.y));
    const v2f gif = permswap_pair(gA);   // .x = i, .y = f
    const v2f ggo = permswap_pair(gB);   // .x = g, .y = o
    c0 = fsigmoid(gif.y) * c0 + fsigmoid(gif.x) * ftanh(ggo.x);
    h0v = fsigmoid(ggo.y) * ftanh(c0);
    h0buf[0][lane & 31] = h0v;           // step 0, parity 0
    // hoist0: h0(0) . W_hh0 for step 1
#pragma unroll
    for (int q = 0; q < 8; ++q) {
      const v2f h01 = {rdlane(h0v, 4*q+0), rdlane(h0v, 4*q+1)};
      const v2f h23 = {rdlane(h0v, 4*q+2), rdlane(h0v, 4*q+3)};
      hoA01 = pkfma(h01, v2f{whA[q].x, whA[q].y}, hoA01);
      hoA23 = pkfma(h23, v2f{whA[q].z, whA[q].w}, hoA23);
      hoB01 = pkfma(h01, v2f{whB[q].x, whB[q].y}, hoB01);
      hoB23 = pkfma(h23, v2f{whB[q].z, whB[q].w}, hoB23);
    }
  } else if (wid == 2) {
    W2_STEP(2)
  }
  __syncthreads();   // h0(0) + gum(2)

  // ---- main loop: phase p = 2..129; wave1 samples step p-2;
  //      wave0 produces h0(p-1); wave2 produces gum(p+1).
  float c1 = 0.f, h1v = 0.f;
  v2f rA01={0.f,0.f}, rA23={0.f,0.f}, rB01={0.f,0.f}, rB23={0.f,0.f};
  float lp_sum = 0.f, ent_sum = 0.f;
  float logit_prev = 0.f;
  int   idx_prev = 0;

  for (int p = 2; p <= 129; ++p) {
    if (wid == 1) {
      const int s = p - 2;
      // finish LSTM1(s): x-part = h0(s) uniform reads x register W_ih1 rows
      // (accumulators carry the hoisted h1(s-1)-dot from last phase's tail)
#pragma unroll
      for (int q = 0; q < 8; ++q) {
        const float4 h4 =
            *reinterpret_cast<const float4*>(&h0buf[s & 1][4 * q]);
        rA01 = pkfma(v2f{h4.x, h4.y}, v2f{wxA[q].x, wxA[q].y}, rA01);
        rA23 = pkfma(v2f{h4.z, h4.w}, v2f{wxA[q].z, wxA[q].w}, rA23);
        rB01 = pkfma(v2f{h4.x, h4.y}, v2f{wxB[q].x, wxB[q].y}, rB01);
        rB23 = pkfma(v2f{h4.z, h4.w}, v2f{wxB[q].z, wxB[q].w}, rB23);
      }
      const float gA1 = bsum1A + ((rA01.x + rA01.y) + (rA23.x + rA23.y));
      const float gB1 = bsum1B + ((rB01.x + rB01.y) + (rB23.x + rB23.y));
      const v2f gif1 = permswap_pair(gA1);
      const v2f ggo1 = permswap_pair(gB1);
      c1  = fsigmoid(gif1.y) * c1 + fsigmoid(gif1.x) * ftanh(ggo1.x);
      h1v = fsigmoid(ggo1.y) * ftanh(c1);

      // logits (lane = op index), pkfma-packed — R23 verbatim
      v2f p01 = {0.f, 0.f}, p23 = {0.f, 0.f};
#pragma unroll
      for (int q = 0; q < 8; ++q) {
        const float4 w = wp4[q];
        p01 = pkfma(v2f{rdlane(h1v, 4*q+0), rdlane(h1v, 4*q+1)},
                    v2f{w.x, w.y}, p01);
        p23 = pkfma(v2f{rdlane(h1v, 4*q+2), rdlane(h1v, 4*q+3)},
                    v2f{w.z, w.w}, p23);
      }
      const float pre   = bp + ((p01.x + p01.y) + (p23.x + p23.y));
      const float logit = 2.5f * ftanh(pre * 0.2f);   // TANH_CONST, 1/TEMP
      const float pert  = logit + gumbuf[s & 3][lane];

      const float M = wave_max64(pert);
      const unsigned long long msk = __ballot(pert == M);
      const int idxu = __ffsll((long long)msk) - 1;   // uniform

      // publish EARLY: arch idx + xdot rows for wave0 (same-phase flag)
      arch_lds[s] = (float)idxu;
      xfer[s & 1][0][lane] = xdot[idxu][lane];
      xfer[s & 1][1][lane] = xdot[idxu][rB];
      __threadfence_block();
      *(volatile int*)&w1flag = s + 1;

      // tail (overlaps wave0's gate work): hoist h1(s).W_hh1 for next phase
      rA01 = v2f{0.f,0.f}; rA23 = v2f{0.f,0.f};
      rB01 = v2f{0.f,0.f}; rB23 = v2f{0.f,0.f};
#pragma unroll
      for (int q = 0; q < 8; ++q) {
        const v2f h01 = {rdlane(h1v, 4*q+0), rdlane(h1v, 4*q+1)};
        const v2f h23 = {rdlane(h1v, 4*q+2), rdlane(h1v, 4*q+3)};
        rA01 = pkfma(h01, v2f{whA[q].x, whA[q].y}, rA01);
        rA23 = pkfma(h23, v2f{whA[q].z, whA[q].w}, rA23);
        rB01 = pkfma(h01, v2f{whB[q].x, whB[q].y}, rB01);
        rB23 = pkfma(h23, v2f{whB[q].z, whB[q].w}, rB23);
      }
      if (s > 0) {
        // deferred softmax stats for step s-1 (register state)
        const float e  = fexp(logit_prev);
        const float E  = wave_sum64(e);
        const float ES = wave_sum64(e * logit_prev);
        const float lse = flog(E);
        const float li  = rdlane(logit_prev, idx_prev);
        lp_sum  += li - lse;
        ent_sum += lse - ES / E;
      }
      logit_prev = logit;
      idx_prev   = idxu;
    } else if (wid == 0) {
      if (p <= 128) {
        // wait for idx(p-2) published THIS phase by wave1
        while (*(volatile int*)&w1flag < p - 1) {}
        __threadfence_block();
        const float xdA = xfer[(p - 2) & 1][0][lane];
        const float xdB = xfer[(p - 2) & 1][1][lane];
        const float gA = (bsum0A + xdA)
                       + ((hoA01.x + hoA01.y) + (hoA23.x + hoA23.y));
        const float gB = (bsum0B + xdB)
                       + ((hoB01.x + hoB01.y) + (hoB23.x + hoB23.y));
        const v2f gif = permswap_pair(gA);
        const v2f ggo = permswap_pair(gB);
        c0 = fsigmoid(gif.y) * c0 + fsigmoid(gif.x) * ftanh(ggo.x);
        h0v = fsigmoid(ggo.y) * ftanh(c0);
        h0buf[(p - 1) & 1][lane & 31] = h0v;
        // hoist0: h0(p-1) . W_hh0 for next phase
        hoA01 = v2f{0.f,0.f}; hoA23 = v2f{0.f,0.f};
        hoB01 = v2f{0.f,0.f}; hoB23 = v2f{0.f,0.f};
#pragma unroll
        for (int q = 0; q < 8; ++q) {
          const v2f h01 = {rdlane(h0v, 4*q+0), rdlane(h0v, 4*q+1)};
          const v2f h23 = {rdlane(h0v, 4*q+2), rdlane(h0v, 4*q+3)};
          hoA01 = pkfma(h01, v2f{whA[q].x, whA[q].y}, hoA01);
          hoA23 = pkfma(h23, v2f{whA[q].z, whA[q].w}, hoA23);
          hoB01 = pkfma(h01, v2f{whB[q].x, whB[q].y}, hoB01);
          hoB23 = pkfma(h23, v2f{whB[q].z, whB[q].w}, hoB23);
        }
      }
    } else {
      if (p <= 126) W2_STEP(p + 1)
    }
    __syncthreads();   // the ONE barrier per step
  }
#undef W2_STEP

  if (wid == 1) {
    // final deferred softmax (step 127)
    const float e  = fexp(logit_prev);
    const float E  = wave_sum64(e);
    const float ES = wave_sum64(e * logit_prev);
    const float lse = flog(E);
    const float li  = rdlane(logit_prev, idx_prev);
    lp_sum  += li - lse;
    ent_sum += lse - ES / E;

    out[2 + lane]      = arch_lds[lane];
    out[2 + 64 + lane] = arch_lds[64 + lane];
    if (lane == 0) { out[0] = lp_sum; out[1] = ent_sum; }
  }
}

}  // namespace

extern "C" void kernel_launch(void* const* d_in, const int* in_sizes, int n_in,
                              void* d_out, int out_size, void* d_ws, size_t ws_size,
                              hipStream_t stream) {
  (void)in_sizes; (void)n_in; (void)d_ws; (void)ws_size; (void)out_size;
  const float* input_vars = (const float*)d_in[0];
  const float* W_ih0 = (const float*)d_in[1];
  const float* W_hh0 = (const float*)d_in[2];
  const float* b_ih0 = (const float*)d_in[3];
  const float* b_hh0 = (const float*)d_in[4];
  const float* W_ih1 = (const float*)d_in[5];
  const float* W_hh1 = (const float*)d_in[6];
  const float* b_ih1 = (const float*)d_in[7];
  const float* b_hh1 = (const float*)d_in[8];
  const float* embd  = (const float*)d_in[9];
  const float* W_pred = (const float*)d_in[10];
  const float* b_pred = (const float*)d_in[11];
  float* out = (float*)d_out;

  hipLaunchKernelGGL(ctrl_kernel, dim3(1), dim3(192), 0, stream,
                     input_vars, W_ih0, W_hh0, b_ih0, b_hh0,
                     W_ih1, W_hh1, b_ih1, b_hh1,
                     embd, W_pred, b_pred, out);
}

// Round 25
// 128.570 us; speedup vs baseline: 1.0557x; 1.0557x over previous
//
#include <hip/hip_runtime.h>
#include <stdint.h>

namespace {

typedef float v2f __attribute__((ext_vector_type(2)));
typedef int   v2i __attribute__((ext_vector_type(2)));

constexpr int H      = 32;    // LSTM_SIZE
constexpr int NEDGE  = 128;
constexpr float TINY   = 1.1754943508222875e-38f;  // finfo(f32).tiny
constexpr float L2E    = 1.4426950408889634f;      // log2(e)
constexpr float LN2    = 0.6931471805599453f;

__device__ __forceinline__ void tf_round(uint32_t& x0, uint32_t& x1, int r) {
  x0 += x1;
  x1 = (x1 << r) | (x1 >> (32 - r));
  x1 ^= x0;
}

// Threefry-2x32, 20 rounds — bit-exact JAX threefry2x32_p
__device__ __forceinline__ void tf2x32(uint32_t k0, uint32_t k1,
                                       uint32_t& x0, uint32_t& x1) {
  const uint32_t ks2 = k0 ^ k1 ^ 0x1BD11BDAu;
  x0 += k0; x1 += k1;
  tf_round(x0,x1,13); tf_round(x0,x1,15); tf_round(x0,x1,26); tf_round(x0,x1, 6);
  x0 += k1;  x1 += ks2 + 1u;
  tf_round(x0,x1,17); tf_round(x0,x1,29); tf_round(x0,x1,16); tf_round(x0,x1,24);
  x0 += ks2; x1 += k0 + 2u;
  tf_round(x0,x1,13); tf_round(x0,x1,15); tf_round(x0,x1,26); tf_round(x0,x1, 6);
  x0 += k0;  x1 += k1 + 3u;
  tf_round(x0,x1,17); tf_round(x0,x1,29); tf_round(x0,x1,16); tf_round(x0,x1,24);
  x0 += k1;  x1 += ks2 + 4u;
  tf_round(x0,x1,13); tf_round(x0,x1,15); tf_round(x0,x1,26); tf_round(x0,x1, 6);
  x0 += ks2; x1 += k0 + 5u;
}

// ---- native-instruction transcendentals
__device__ __forceinline__ float fexp(float x) {       // e^x
  return __builtin_amdgcn_exp2f(x * L2E);
}
__device__ __forceinline__ float flog(float x) {       // ln(x)
  return __builtin_amdgcn_logf(x) * LN2;
}
__device__ __forceinline__ float fsigmoid(float x) {   // 1/(1+e^-x)
  return __builtin_amdgcn_rcpf(1.0f + __builtin_amdgcn_exp2f(-x * L2E));
}
__device__ __forceinline__ float ftanh(float x) {
  const float ax = __builtin_fabsf(x);
  const float t  = __builtin_amdgcn_exp2f(ax * (-2.0f * L2E));  // e^(-2|x|)
  const float r  = (1.0f - t) * __builtin_amdgcn_rcpf(1.0f + t);
  return __builtin_copysignf(r, x);
}

__device__ __forceinline__ float rdlane(float v, int i) {
  return __int_as_float(__builtin_amdgcn_readlane(__float_as_int(v), i));
}

template <int CTRL>
__device__ __forceinline__ float dppf(float v) {
  return __int_as_float(__builtin_amdgcn_update_dpp(
      __float_as_int(v), __float_as_int(v), CTRL, 0xF, 0xF, false));
}

// 64-lane reductions: DPP butterfly within rows of 16, then 4 readlanes.
__device__ __forceinline__ float wave_sum64(float v) {
  v += dppf<0xB1>(v);
  v += dppf<0x4E>(v);
  v += dppf<0x141>(v);
  v += dppf<0x140>(v);
  return (rdlane(v, 15) + rdlane(v, 31)) + (rdlane(v, 47) + rdlane(v, 63));
}

__device__ __forceinline__ float wave_max64(float v) {
  v = fmaxf(v, dppf<0xB1>(v));
  v = fmaxf(v, dppf<0x4E>(v));
  v = fmaxf(v, dppf<0x141>(v));
  v = fmaxf(v, dppf<0x140>(v));
  return fmaxf(fmaxf(rdlane(v, 15), rdlane(v, 31)),
               fmaxf(rdlane(v, 47), rdlane(v, 63)));
}

__device__ __forceinline__ v2f pkfma(v2f a, v2f b, v2f c) {
  return __builtin_elementwise_fma(a, b, c);   // -> v_pk_fma_f32
}

// Cross-half swap (gfx950 VALU): r.x = g[lane&31] (i or g gate row),
// r.y = g[(lane&31)+32] (f or o gate row), identical in both halves.
__device__ __forceinline__ v2f permswap_pair(float g) {
  const v2i r = __builtin_amdgcn_permlane32_swap(
      __float_as_int(g), __float_as_int(g), false, false);
  return v2f{__int_as_float(r.x), __int_as_float(r.y)};
}

__global__ __launch_bounds__(192, 1)
void ctrl_kernel(const float* __restrict__ input_vars,
                 const float* __restrict__ W_ih0, const float* __restrict__ W_hh0,
                 const float* __restrict__ b_ih0, const float* __restrict__ b_hh0,
                 const float* __restrict__ W_ih1, const float* __restrict__ W_hh1,
                 const float* __restrict__ b_ih1, const float* __restrict__ b_hh1,
                 const float* __restrict__ embd,
                 const float* __restrict__ W_pred, const float* __restrict__ b_pred,
                 float* __restrict__ out) {
  const int tid  = threadIdx.x;  // w0: LSTM0; w1: LSTM1+sample; w2: PRNG+softmax
  const int lane = tid & 63;
  const int wid  = tid >> 6;
  const int rB   = lane + 64;

  __shared__ __align__(16) float embd_lds[65 * H]; // rows 0-63 embd, 64 = input
  __shared__ __align__(16) float xdot[65][128];    // W_ih0 rows . x_op (33.3 KiB)
  __shared__ __align__(16) float h0buf[2][H];      // w0 -> w1, dbuf by t&1
  __shared__ __align__(16) float gumbuf[4][64];    // w2 -> w1, 4-deep (t+2 ahead)
  __shared__ __align__(16) float xfer[2][2][64];   // w1 -> w0: xdot rows, dbuf
  __shared__ __align__(16) float logitbuf[2][64];  // w1 -> w2, dbuf by t&1
  __shared__ __align__(16) float arch_lds[NEDGE];

  // waves 0/1 stage embd + input row
  if (wid < 2) {
#pragma unroll
    for (int j = 0; j < 4; ++j)
      reinterpret_cast<float4*>(embd_lds)[(tid & 127) + 128 * j] =
          reinterpret_cast<const float4*>(embd)[(tid & 127) + 128 * j];
    if (tid < 8)
      reinterpret_cast<float4*>(&embd_lds[64 * H])[tid] =
          reinterpret_cast<const float4*>(input_vars)[tid];
  }

  // Register weights: wave0 = W_ih0 (table) + W_hh0; wave1 = W_ih1 + W_hh1 + W_pred.
  const float* WX = (wid == 1) ? W_ih1 : W_ih0;
  const float* WH = (wid == 1) ? W_hh1 : W_hh0;
  float4 wxA[8], wxB[8], whA[8], whB[8];
#pragma unroll
  for (int q = 0; q < 8; ++q) {
    wxA[q] = reinterpret_cast<const float4*>(WX + lane * H)[q];
    wxB[q] = reinterpret_cast<const float4*>(WX + rB * H)[q];
    whA[q] = reinterpret_cast<const float4*>(WH + lane * H)[q];
    whB[q] = reinterpret_cast<const float4*>(WH + rB * H)[q];
  }
  float4 wp4[8];
  if (wid == 1) {
#pragma unroll
    for (int q = 0; q < 8; ++q)
      wp4[q] = reinterpret_cast<const float4*>(W_pred + lane * H)[q];
  }
  const float bsum0A = b_ih0[lane] + b_hh0[lane];
  const float bsum0B = b_ih0[rB]   + b_hh0[rB];
  const float bsum1A = b_ih1[lane] + b_hh1[lane];
  const float bsum1B = b_ih1[rB]   + b_hh1[rB];
  const float bp = b_pred[lane];

  float c0 = 0.f, h0v = 0.f;           // wave0 LSTM0 state
  float c1 = 0.f, h1v = 0.f;           // wave1 LSTM1 state
  v2f hoA01={0.f,0.f}, hoA23={0.f,0.f}, hoB01={0.f,0.f}, hoB23={0.f,0.f};
  uint32_t k0 = 0u, k1 = 42u;          // key chain (wave2)
  uint32_t s0c = 0u, s1c = 0u;         // subkey carried phase1 -> phase2
  float lp_sum = 0.f, ent_sum = 0.f;   // wave2

  if (wid == 2) {
    // PRNG prologue: gum(0), gum(1) — exact cipher sequence as R23
#pragma unroll 1
    for (int p = 0; p < 2; ++p) {
      uint32_t r0 = 0u, r1 = (uint32_t)(lane & 1);
      tf2x32(k0, k1, r0, r1);
      const uint32_t n0 = (uint32_t)__builtin_amdgcn_readlane((int)r0, 0);
      const uint32_t n1 = (uint32_t)__builtin_amdgcn_readlane((int)r1, 0);
      const uint32_t s0 = (uint32_t)__builtin_amdgcn_readlane((int)r0, 1);
      const uint32_t s1 = (uint32_t)__builtin_amdgcn_readlane((int)r1, 1);
      uint32_t x0 = 0u, x1 = (uint32_t)lane;
      tf2x32(s0, s1, x0, x1);
      const uint32_t bits = x0 ^ x1;
      k0 = n0; k1 = n1;
      float u = __uint_as_float(0x3f800000u | (bits >> 9)) - 1.0f;
      u = fmaxf(u + TINY, TINY);
      gumbuf[p][lane] = -flog(-flog(u));
    }
  }
  __syncthreads();          // embd staged; gum(0,1) ready

  // ---- phase0: wave0 builds xdot table from register W_ih0 (R24-validated)
  if (wid == 0) {
    for (int op = 0; op < 65; ++op) {
      v2f xA01={0.f,0.f}, xA23={0.f,0.f}, xB01={0.f,0.f}, xB23={0.f,0.f};
#pragma unroll
      for (int q = 0; q < 8; ++q) {
        const float4 x4 =
            *reinterpret_cast<const float4*>(&embd_lds[op * H + 4 * q]);
        xA01 = pkfma(v2f{x4.x, x4.y}, v2f{wxA[q].x, wxA[q].y}, xA01);
        xA23 = pkfma(v2f{x4.z, x4.w}, v2f{wxA[q].z, wxA[q].w}, xA23);
        xB01 = pkfma(v2f{x4.x, x4.y}, v2f{wxB[q].x, wxB[q].y}, xB01);
        xB23 = pkfma(v2f{x4.z, x4.w}, v2f{wxB[q].z, wxB[q].w}, xB23);
      }
      xdot[op][lane] = (xA01.x + xA01.y) + (xA23.x + xA23.y);
      xdot[op][rB]   = (xB01.x + xB01.y) + (xB23.x + xB23.y);
    }
  }
  __syncthreads();          // table ready

  for (int t = 0; t < NEDGE; ++t) {
    // wave1 LSTM1 accumulators (phase1 hoisted -> phase2 finish)
    v2f rA01={0.f,0.f}, rA23={0.f,0.f}, rB01={0.f,0.f}, rB23={0.f,0.f};

    // ======== phase1 ========
    if (wid == 0) {
      // gates0(t): xdot table lookup (t=0: input row 64) + hoisted h-dot
      const float xdA = (t == 0) ? xdot[64][lane] : xfer[t & 1][0][lane];
      const float xdB = (t == 0) ? xdot[64][rB]   : xfer[t & 1][1][lane];
      const float gA = (bsum0A + xdA)
                     + ((hoA01.x + hoA01.y) + (hoA23.x + hoA23.y));
      const float gB = (bsum0B + xdB)
                     + ((hoB01.x + hoB01.y) + (hoB23.x + hoB23.y));
      const v2f gif = permswap_pair(gA);   // .x = i, .y = f
      const v2f ggo = permswap_pair(gB);   // .x = g, .y = o
      c0 = fsigmoid(gif.y) * c0 + fsigmoid(gif.x) * ftanh(ggo.x);
      h0v = fsigmoid(ggo.y) * ftanh(c0);
      h0buf[t & 1][lane & 31] = h0v;       // 2 lanes/addr same data: free
    } else if (wid == 1) {
      // hoisted LSTM1 h1(t-1)-dot via rdlane pairs against REGISTER W_hh1
#pragma unroll
      for (int q = 0; q < 8; ++q) {
        const v2f h01 = {rdlane(h1v, 4*q+0), rdlane(h1v, 4*q+1)};
        const v2f h23 = {rdlane(h1v, 4*q+2), rdlane(h1v, 4*q+3)};
        rA01 = pkfma(h01, v2f{whA[q].x, whA[q].y}, rA01);
        rA23 = pkfma(h23, v2f{whA[q].z, whA[q].w}, rA23);
        rB01 = pkfma(h01, v2f{whB[q].x, whB[q].y}, rB01);
        rB23 = pkfma(h23, v2f{whB[q].z, whB[q].w}, rB23);
      }
    } else {
      // cipher1 for step t+2: key_{t+2} -> (key_{t+3}, sub_{t+2})
      uint32_t r0 = 0u, r1 = (uint32_t)(lane & 1);
      tf2x32(k0, k1, r0, r1);
      k0  = (uint32_t)__builtin_amdgcn_readlane((int)r0, 0);
      k1  = (uint32_t)__builtin_amdgcn_readlane((int)r1, 0);
      s0c = (uint32_t)__builtin_amdgcn_readlane((int)r0, 1);
      s1c = (uint32_t)__builtin_amdgcn_readlane((int)r1, 1);
    }
    __syncthreads();   // M: h0(t) visible to wave1

    // ======== phase2 ========
    if (wid == 0) {
      // hoisted LSTM0 h0(t)-dot for step t+1 (own regs x REGISTER W_hh0)
      hoA01 = v2f{0.f,0.f}; hoA23 = v2f{0.f,0.f};
      hoB01 = v2f{0.f,0.f}; hoB23 = v2f{0.f,0.f};
#pragma unroll
      for (int q = 0; q < 8; ++q) {
        const v2f h01 = {rdlane(h0v, 4*q+0), rdlane(h0v, 4*q+1)};
        const v2f h23 = {rdlane(h0v, 4*q+2), rdlane(h0v, 4*q+3)};
        hoA01 = pkfma(h01, v2f{whA[q].x, whA[q].y}, hoA01);
        hoA23 = pkfma(h23, v2f{whA[q].z, whA[q].w}, hoA23);
        hoB01 = pkfma(h01, v2f{whB[q].x, whB[q].y}, hoB01);
        hoB23 = pkfma(h23, v2f{whB[q].z, whB[q].w}, hoB23);
      }
    } else if (wid == 1) {
      // finish LSTM1(t): x-part = h0(t) uniform reads x register W_ih1 rows
#pragma unroll
      for (int q = 0; q < 8; ++q) {
        const float4 h4 =
            *reinterpret_cast<const float4*>(&h0buf[t & 1][4 * q]);
        rA01 = pkfma(v2f{h4.x, h4.y}, v2f{wxA[q].x, wxA[q].y}, rA01);
        rA23 = pkfma(v2f{h4.z, h4.w}, v2f{wxA[q].z, wxA[q].w}, rA23);
        rB01 = pkfma(v2f{h4.x, h4.y}, v2f{wxB[q].x, wxB[q].y}, rB01);
        rB23 = pkfma(v2f{h4.z, h4.w}, v2f{wxB[q].z, wxB[q].w}, rB23);
      }
      const float gA1 = bsum1A + ((rA01.x + rA01.y) + (rA23.x + rA23.y));
      const float gB1 = bsum1B + ((rB01.x + rB01.y) + (rB23.x + rB23.y));
      const v2f gif1 = permswap_pair(gA1);
      const v2f ggo1 = permswap_pair(gB1);
      c1  = fsigmoid(gif1.y) * c1 + fsigmoid(gif1.x) * ftanh(ggo1.x);
      h1v = fsigmoid(ggo1.y) * ftanh(c1);

      // logits (lane = op index), pkfma-packed
      v2f p01 = {0.f, 0.f}, p23 = {0.f, 0.f};
#pragma unroll
      for (int q = 0; q < 8; ++q) {
        const float4 w = wp4[q];
        p01 = pkfma(v2f{rdlane(h1v, 4*q+0), rdlane(h1v, 4*q+1)},
                    v2f{w.x, w.y}, p01);
        p23 = pkfma(v2f{rdlane(h1v, 4*q+2), rdlane(h1v, 4*q+3)},
                    v2f{w.z, w.w}, p23);
      }
      const float pre   = bp + ((p01.x + p01.y) + (p23.x + p23.y));
      const float logit = 2.5f * ftanh(pre * 0.2f);   // TANH_CONST, 1/TEMP
      const float pert  = logit + gumbuf[t & 3][lane];

      // argmax via DPP-max + ballot (tie -> lowest index)
      const float M = wave_max64(pert);
      const unsigned long long msk = __ballot(pert == M);
      const int idxu = __ffsll((long long)msk) - 1;

      arch_lds[t] = (float)idxu;
      logitbuf[t & 1][lane] = logit;           // for wave2's softmax(t)
      // hand next-step xdot rows to wave0
      xfer[(t + 1) & 1][0][lane] = xdot[idxu][lane];
      xfer[(t + 1) & 1][1][lane] = xdot[idxu][rB];
    } else {
      // cipher2(sub_{t+2}) -> gum(t+2); write is 2 steps ahead of the reader
      uint32_t x0 = 0u, x1 = (uint32_t)lane;
      tf2x32(s0c, s1c, x0, x1);
      const uint32_t bits = x0 ^ x1;
      float u = __uint_as_float(0x3f800000u | (bits >> 9)) - 1.0f;
      u = fmaxf(u + TINY, TINY);
      gumbuf[(t + 2) & 3][lane] = -flog(-flog(u));
      if (t > 0) {
        // deferred softmax stats for step t-1 (logitbuf + arch from phase2(t-1))
        const float lg  = logitbuf[(t - 1) & 1][lane];
        const int  idxp = (int)arch_lds[t - 1];
        const float e  = fexp(lg);
        const float E  = wave_sum64(e);
        const float ES = wave_sum64(e * lg);
        const float lse = flog(E);
        const float li  = logitbuf[(t - 1) & 1][idxp];
        lp_sum  += li - lse;
        ent_sum += lse - ES / E;
      }
    }
    __syncthreads();   // E: xfer(t+1), logit(t), gum(t+2) visible
  }

  if (wid == 2) {
    // final deferred softmax (t = 127)
    const float lg  = logitbuf[127 & 1][lane];
    const int  idxp = (int)arch_lds[127];
    const float e  = fexp(lg);
    const float E  = wave_sum64(e);
    const float ES = wave_sum64(e * lg);
    const float lse = flog(E);
    const float li  = logitbuf[127 & 1][idxp];
    lp_sum  += li - lse;
    ent_sum += lse - ES / E;
    if (lane == 0) { out[0] = lp_sum; out[1] = ent_sum; }
  } else if (wid == 1) {
    out[2 + lane]      = arch_lds[lane];
    out[2 + 64 + lane] = arch_lds[64 + lane];
  }
}

}  // namespace

extern "C" void kernel_launch(void* const* d_in, const int* in_sizes, int n_in,
                              void* d_out, int out_size, void* d_ws, size_t ws_size,
                              hipStream_t stream) {
  (void)in_sizes; (void)n_in; (void)d_ws; (void)ws_size; (void)out_size;
  const float* input_vars = (const float*)d_in[0];
  const float* W_ih0 = (const float*)d_in[1];
  const float* W_hh0 = (const float*)d_in[2];
  const float* b_ih0 = (const float*)d_in[3];
  const float* b_hh0 = (const float*)d_in[4];
  const float* W_ih1 = (const float*)d_in[5];
  const float* W_hh1 = (const float*)d_in[6];
  const float* b_ih1 = (const float*)d_in[7];
  const float* b_hh1 = (const float*)d_in[8];
  const float* embd  = (const float*)d_in[9];
  const float* W_pred = (const float*)d_in[10];
  const float* b_pred = (const float*)d_in[11];
  float* out = (float*)d_out;

  hipLaunchKernelGGL(ctrl_kernel, dim3(1), dim3(192), 0, stream,
                     input_vars, W_ih0, W_hh0, b_ih0, b_hh0,
                     W_ih1, W_hh1, b_ih1, b_hh1,
                     embd, W_pred, b_pred, out);
}